// Round 18
// baseline (122.891 us; speedup 1.0000x reference)
//
#include <hip/hip_runtime.h>
#include <stdint.h>

typedef __bf16 bf16;
typedef bf16 bf16x8 __attribute__((ext_vector_type(8)));
typedef bf16 bf16x4 __attribute__((ext_vector_type(4)));
typedef float f32x4 __attribute__((ext_vector_type(4)));
typedef float f32x16 __attribute__((ext_vector_type(16)));
typedef unsigned int uint;
typedef uint u32x4 __attribute__((ext_vector_type(4)));

#define MFMA16(a, b, c) __builtin_amdgcn_mfma_f32_16x16x32_bf16(a, b, c, 0, 0, 0)
#define MFMA32(a, b, c) __builtin_amdgcn_mfma_f32_32x32x16_bf16(a, b, c, 0, 0, 0)

static constexpr int Bsz = 2, T = 2048, E = 1024, H = 16, Dh = 64;
// softmax scale folded into Q at projection; exp2-domain: 1/sqrt(64) * log2(e)
static constexpr float QSCALE = 0.125f * 1.44269504088896f;

__device__ __forceinline__ float exp2fast(float x) {
#if __has_builtin(__builtin_amdgcn_exp2f)
    return __builtin_amdgcn_exp2f(x);
#else
    return exp2f(x);
#endif
}

// async global->LDS, 16B per lane. LDS dest must be wave-uniform base (HW adds lane*16).
__device__ __forceinline__ void gll16(const bf16* g, bf16* l) {
    __builtin_amdgcn_global_load_lds((const __attribute__((address_space(1))) uint*)g,
                                     (__attribute__((address_space(3))) uint*)l, 16, 0, 0);
}

// ---- bf16 tile: ROWS x 64, swizzled LDS[r][c8] = G[r][c8^(r&7)] (attn-verified) ----
template <int ROWS>
__device__ __forceinline__ void stage_b16(bf16* lds, const bf16* g, int ldg, int wave, int lane) {
    const int rsub = lane >> 3;         // row within 8-row slab
    const int csw = (lane & 7) ^ rsub;  // pre-swizzled source chunk
#pragma unroll
    for (int i = 0; i < ROWS / 32; ++i) {
        const int row = wave * (ROWS / 4) + i * 8;  // wave-uniform slab base
        gll16(g + (size_t)(row + rsub) * ldg + csw * 8, lds + row * 64);
    }
}
__device__ __forceinline__ bf16x8 frag_b16(const bf16* lds, int r, int cc) {
    return *(const bf16x8*)(lds + r * 64 + ((cc ^ (r & 7)) << 3));
}

// ---- fp32 tile: ROWS x 64 f32, swizzled LDS[r][c4] = G[r][c4^(r&15)] (r15-verified) ----
template <int ROWS>
__device__ __forceinline__ void stage_f32lds(float* lds, const float* g, int ldg,
                                             int wave, int lane) {
    const int rsub = lane >> 4;  // row within 4-row slab
#pragma unroll
    for (int i = 0; i < ROWS / 16; ++i) {
        const int slab = wave * (ROWS / 16) + i;
        const int row0 = slab * 4;  // wave-uniform
        const int src = (lane & 15) ^ ((((slab & 3)) << 2) | rsub);  // (row&15)
        gll16((const bf16*)(g + (size_t)(row0 + rsub) * ldg + src * 4),
              (bf16*)(lds + row0 * 64));
    }
}
__device__ __forceinline__ bf16x8 frag_f32(const float* lds, int r, int lc0) {
    const f32x4 u0 = *(const f32x4*)(lds + r * 64 + ((lc0 ^ (r & 15)) << 2));
    const f32x4 u1 = *(const f32x4*)(lds + r * 64 + (((lc0 + 1) ^ (r & 15)) << 2));
    bf16x8 a = {(bf16)u0.x, (bf16)u0.y, (bf16)u0.z, (bf16)u0.w,
                (bf16)u1.x, (bf16)u1.y, (bf16)u1.z, (bf16)u1.w};
    return a;
}

// ---- Generic double-buffered GEMM body: Y[M,N] = A[M,K] @ B[N,K]^T (+bias).
// Either operand may be fp32 (staged raw via global_load_lds, converted at
// LDS-read time -> bit-identical to pre-cvt) or bf16. Counted-vmcnt pipeline:
// next tile's loads stay in flight across the barrier.
template <bool AF32, bool BF32, int MF, int NF, bool OUTF32>
__device__ __forceinline__ void gemm_dbuf2(char* smem, const void* Ap, const void* Bp,
                                           bf16* Yb, float* Yf, const float* bias,
                                           int m0, int n0, int K, int ldy, float oscale) {
    constexpr int BM = MF * 32, BN = NF * 32;
    constexpr int ASZ = BM * 64 * (AF32 ? 4 : 2);
    constexpr int SET = ASZ + BN * 64 * (BF32 ? 4 : 2);
    constexpr int LD = (AF32 ? BM / 16 : BM / 32) + (BF32 ? BN / 16 : BN / 32);
    const int tid = threadIdx.x, lane = tid & 63, wave = tid >> 6;
    const int wm = wave >> 1, wn = wave & 1;
    const int fr = lane & 15, kg16 = lane >> 4;

    const float* A32 = (const float*)Ap;
    const bf16* A16 = (const bf16*)Ap;
    const float* B32 = (const float*)Bp;
    const bf16* B16 = (const bf16*)Bp;

    f32x4 acc[MF][NF] = {};

    auto stageA = [&](char* dst, int k0) {
        if constexpr (AF32)
            stage_f32lds<BM>((float*)dst, A32 + (size_t)m0 * K + k0, K, wave, lane);
        else
            stage_b16<BM>((bf16*)dst, A16 + (size_t)m0 * K + k0, K, wave, lane);
    };
    auto stageB = [&](char* dst, int k0) {
        if constexpr (BF32)
            stage_f32lds<BN>((float*)dst, B32 + (size_t)n0 * K + k0, K, wave, lane);
        else
            stage_b16<BN>((bf16*)dst, B16 + (size_t)n0 * K + k0, K, wave, lane);
    };

    // prologue: stage tile 0 into set 0
    stageA(smem, 0);
    stageB(smem + ASZ, 0);

    const int NS = K / 64;
    int cur = 0;
#pragma unroll 1
    for (int s = 0; s < NS; ++s) {
        if (s + 1 < NS) {
            char* dst = smem + (cur ^ 1) * SET;
            stageA(dst, (s + 1) * 64);
            stageB(dst + ASZ, (s + 1) * 64);
            if constexpr (LD == 8)
                asm volatile("s_waitcnt vmcnt(8)" ::: "memory");  // cur landed
            else if constexpr (LD == 6)
                asm volatile("s_waitcnt vmcnt(6)" ::: "memory");
            else
                asm volatile("s_waitcnt vmcnt(0)" ::: "memory");
        } else {
            asm volatile("s_waitcnt vmcnt(0)" ::: "memory");
        }
        __builtin_amdgcn_s_barrier();
        asm volatile("" ::: "memory");

        const char* At = smem + cur * SET;
        const char* Bt = At + ASZ;
#pragma unroll
        for (int kk = 0; kk < 64; kk += 32) {
            bf16x8 af[MF], bfr[NF];
#pragma unroll
            for (int f = 0; f < MF; ++f) {
                const int r = wm * (BM / 2) + f * 16 + fr;
                if constexpr (AF32)
                    af[f] = frag_f32((const float*)At, r, (kk >> 2) + (kg16 << 1));
                else
                    af[f] = frag_b16((const bf16*)At, r, (kk >> 3) + kg16);
            }
#pragma unroll
            for (int f = 0; f < NF; ++f) {
                const int r = wn * (BN / 2) + f * 16 + fr;
                if constexpr (BF32)
                    bfr[f] = frag_f32((const float*)Bt, r, (kk >> 2) + (kg16 << 1));
                else
                    bfr[f] = frag_b16((const bf16*)Bt, r, (kk >> 3) + kg16);
            }
            __builtin_amdgcn_s_setprio(1);
#pragma unroll
            for (int mf = 0; mf < MF; ++mf)
#pragma unroll
                for (int nf = 0; nf < NF; ++nf)
                    acc[mf][nf] = MFMA16(af[mf], bfr[nf], acc[mf][nf]);
            __builtin_amdgcn_s_setprio(0);
        }
        asm volatile("" ::: "memory");
        __builtin_amdgcn_s_barrier();
        cur ^= 1;
    }
    const int rb = (lane >> 4) << 2;
#pragma unroll
    for (int mf = 0; mf < MF; ++mf)
#pragma unroll
        for (int nf = 0; nf < NF; ++nf) {
            int n = n0 + wn * (BN / 2) + nf * 16 + fr;
            float bn = 0.f;
            if constexpr (OUTF32) bn = bias[n];
#pragma unroll
            for (int r = 0; r < 4; ++r) {
                int mm = m0 + wm * (BM / 2) + mf * 16 + rb + r;
                float v = acc[mf][nf][r];
                if constexpr (OUTF32)
                    Yf[(size_t)mm * ldy + n] = v + bn;
                else
                    Yb[(size_t)mm * ldy + n] = (bf16)(v * oscale);
            }
        }
}

// ---- Single-buffer fallback body (only used when ws < 40 MB) ----
template <bool AF32, bool BF32, int MF, int NF, bool OUTF32>
__device__ __forceinline__ void gemm_body(char* smem, const void* Ap, const void* Bp,
                                          bf16* Yb, float* Yf, const float* bias,
                                          int m0, int n0, int K, int ldy, float oscale) {
    constexpr int BM = MF * 32, BN = NF * 32;
    constexpr int ASZ = BM * 64 * (AF32 ? 4 : 2);
    const int tid = threadIdx.x, lane = tid & 63, wave = tid >> 6;
    const int wm = wave >> 1, wn = wave & 1;
    const int fr = lane & 15, kg16 = lane >> 4;
    f32x4 acc[MF][NF] = {};
    for (int k0 = 0; k0 < K; k0 += 64) {
        if constexpr (AF32)
            stage_f32lds<BM>((float*)smem, (const float*)Ap + (size_t)m0 * K + k0, K, wave, lane);
        else
            stage_b16<BM>((bf16*)smem, (const bf16*)Ap + (size_t)m0 * K + k0, K, wave, lane);
        if constexpr (BF32)
            stage_f32lds<BN>((float*)(smem + ASZ), (const float*)Bp + (size_t)n0 * K + k0,
                             K, wave, lane);
        else
            stage_b16<BN>((bf16*)(smem + ASZ), (const bf16*)Bp + (size_t)n0 * K + k0,
                          K, wave, lane);
        __syncthreads();
#pragma unroll
        for (int kk = 0; kk < 64; kk += 32) {
            bf16x8 af[MF], bfr[NF];
#pragma unroll
            for (int f = 0; f < MF; ++f) {
                const int r = wm * (BM / 2) + f * 16 + fr;
                if constexpr (AF32)
                    af[f] = frag_f32((const float*)smem, r, (kk >> 2) + (kg16 << 1));
                else
                    af[f] = frag_b16((const bf16*)smem, r, (kk >> 3) + kg16);
            }
#pragma unroll
            for (int f = 0; f < NF; ++f) {
                const int r = wn * (BN / 2) + f * 16 + fr;
                if constexpr (BF32)
                    bfr[f] = frag_f32((const float*)(smem + ASZ), r, (kk >> 2) + (kg16 << 1));
                else
                    bfr[f] = frag_b16((const bf16*)(smem + ASZ), r, (kk >> 3) + kg16);
            }
#pragma unroll
            for (int mf = 0; mf < MF; ++mf)
#pragma unroll
                for (int nf = 0; nf < NF; ++nf)
                    acc[mf][nf] = MFMA16(af[mf], bfr[nf], acc[mf][nf]);
        }
        __syncthreads();
    }
    const int rb = (lane >> 4) << 2;
#pragma unroll
    for (int mf = 0; mf < MF; ++mf)
#pragma unroll
        for (int nf = 0; nf < NF; ++nf) {
            int n = n0 + wn * (BN / 2) + nf * 16 + fr;
            float bn = 0.f;
            if constexpr (OUTF32) bn = bias[n];
#pragma unroll
            for (int r = 0; r < 4; ++r) {
                int mm = m0 + wm * (BM / 2) + mf * 16 + rb + r;
                float v = acc[mf][nf][r];
                if constexpr (OUTF32)
                    Yf[(size_t)mm * ldy + n] = v + bn;
                else
                    Yb[(size_t)mm * ldy + n] = (bf16)(v * oscale);
            }
        }
}

// ---- weights-only fp32 -> bf16 conversion (x operands read fp32 by GEMMs) ----
__global__ __launch_bounds__(256) void cvt_w(const float* Wq, const float* Wk,
                                             const float* Wv, const float* Wo,
                                             bf16* Wqc, bf16* Wkc, bf16* Wvc, bf16* Woc) {
    const size_t NW = (size_t)E * E;
    const size_t nwork = (4 * NW) >> 2;
    for (size_t t = (size_t)blockIdx.x * 256 + threadIdx.x; t < nwork;
         t += (size_t)gridDim.x * 256) {
        size_t i = t << 2;
        size_t w = i / NW;
        size_t off = i - w * NW;
        const float* s = w == 0 ? Wq : (w == 1 ? Wk : (w == 2 ? Wv : Wo));
        bf16* d = w == 0 ? Wqc : (w == 1 ? Wkc : (w == 2 ? Wvc : Woc));
        const float4 x = *(const float4*)(s + off);
        bf16x4 y = {(bf16)x.x, (bf16)x.y, (bf16)x.z, (bf16)x.w};
        *(bf16x4*)(d + off) = y;
    }
}

// ---- Fused Q/K/V^T projections, all dbuf, x read fp32 directly ----
// wid 0..511: Q = q @ Wq^T (64x128 tiles, A fp32);  512..1023: K likewise;
// 1024..1535: Vt_b = Wv @ v_b^T (128x64 tiles, B fp32). 64 KB LDS both ways.
__global__ __launch_bounds__(256) void proj_qkv(
    const float* q32, const float* k32, const float* v32,
    const bf16* Wqc, const bf16* Wkc, const bf16* Wvc,
    bf16* Qb, bf16* Kb, bf16* Vt) {
    __shared__ __align__(16) char smem[64 * 1024];
    const int bid = blockIdx.x;
    const int wid = (bid & 7) * 192 + (bid >> 3);  // 1536 % 8 == 0: bijective
    if (wid < 1024) {
        const int s = wid >> 9;  // 0=Q (QSCALE), 1=K
        const int t = wid & 511;
        const int m0 = (t >> 3) * 64, n0 = (t & 7) * 128;
        gemm_dbuf2<true, false, 2, 4, false>(smem, s ? k32 : q32, s ? Wkc : Wqc,
                                             s ? Kb : Qb, nullptr, nullptr, m0, n0, E, E,
                                             s ? 1.0f : QSCALE);
    } else {
        const int r = wid - 1024;
        const int b = r >> 8, rr = r & 255;
        const int m0 = (rr >> 5) * 128, n0 = (rr & 31) * 64;
        gemm_dbuf2<false, true, 4, 2, false>(smem, Wvc, v32 + (size_t)b * T * E,
                                             Vt + (size_t)b * E * T, nullptr, nullptr,
                                             m0, n0, E, T, 1.0f);
    }
}

// Output projection dbuf: 48 KB, 512 blocks.
__global__ __launch_bounds__(256) void out_proj_db(const bf16* Xb, const bf16* W16,
                                                   float* Y, const float* bias) {
    __shared__ __align__(16) char smem[48 * 1024];
    const int bid = blockIdx.x;
    const int wid = (bid & 7) * 64 + (bid >> 3);  // 512 % 8 == 0: bijective
    const int m0 = (wid >> 3) * 64, n0 = (wid & 7) * 128;
    gemm_dbuf2<false, false, 2, 4, true>(smem, Xb, W16, nullptr, Y, bias, m0, n0, E, E, 1.0f);
}

// ---- fallback (ws < 40 MB): single-buffer fused path ----
__global__ __launch_bounds__(256) void qkv_proj_fb(
    const float* q32, const float* k32, const float* v32,
    const float* Wq32, const float* Wk32, const float* Wv32,
    bf16* Qb, bf16* Kb, bf16* Vt) {
    __shared__ __align__(16) char smem[64 * 1024];
    const int bid = blockIdx.x;
    const int wid = (bid & 7) * 96 + (bid >> 3);
    if (wid < 512) {
        int s = wid >> 8;
        int t = wid & 255;
        int m0 = (t >> 3) * 128, n0 = (t & 7) * 128;
        gemm_body<true, true, 4, 4, false>(smem, s ? k32 : q32, s ? Wk32 : Wq32,
                                           s ? Kb : Qb, nullptr, nullptr, m0, n0, E, E,
                                           s ? 1.0f : QSCALE);
    } else {
        int r = wid - 512;
        int b = r >> 7, rr = r & 127;
        int m0 = (rr >> 4) * 128, n0 = (rr & 15) * 128;
        gemm_body<true, true, 4, 4, false>(smem, Wv32, v32 + (size_t)b * T * E,
                                           Vt + (size_t)b * E * T, nullptr, nullptr,
                                           m0, n0, E, T, 1.0f);
    }
}
__global__ __launch_bounds__(256) void out_proj_fb(const bf16* Xb, const float* W32,
                                                   float* Y, const float* bias) {
    __shared__ __align__(16) char smem[40 * 1024];
    const int bid = blockIdx.x;
    const int wid = (bid & 7) * 64 + (bid >> 3);
    const int m0 = (wid >> 3) * 64, n0 = (wid & 7) * 128;
    gemm_body<false, true, 2, 4, true>(smem, Xb, W32, nullptr, Y, bias, m0, n0, E, E, 1.0f);
}

// ---------------- Attention: flash, shared LDS-staged K/V tiles ------------
__device__ __forceinline__ uint pkbf(float a, float b) {
    uint16_t x = __builtin_bit_cast(uint16_t, (bf16)a);
    uint16_t y = __builtin_bit_cast(uint16_t, (bf16)b);
    return (uint)x | ((uint)y << 16);
}

template <int DMODE>
__device__ __forceinline__ void attn_tile64(const bf16* KL, const bf16* VL,
                                            int l31, int hi, int swz,
                                            const bf16x8 (&qf)[4],
                                            f32x16& o0, f32x16& o1, float& m, float& l) {
    constexpr int NCC = (DMODE == 2) ? 2 : 4;
    f32x16 s0 = {}, s1 = {};
    {
        bf16x8 kf[4];
#pragma unroll
        for (int t = 0; t < 4; ++t)
            kf[t] = *(const bf16x8*)(KL + l31 * 64 + ((((t << 1) | hi) ^ swz) << 3));
        __builtin_amdgcn_s_setprio(1);
#pragma unroll
        for (int t = 0; t < 4; ++t) s0 = MFMA32(kf[t], qf[t], s0);
        __builtin_amdgcn_s_setprio(0);
    }
    if constexpr (DMODE != 2) {
        bf16x8 kf[4];
#pragma unroll
        for (int t = 0; t < 4; ++t)
            kf[t] = *(const bf16x8*)(KL + (32 + l31) * 64 + ((((t << 1) | hi) ^ swz) << 3));
        __builtin_amdgcn_s_setprio(1);
#pragma unroll
        for (int t = 0; t < 4; ++t) s1 = MFMA32(kf[t], qf[t], s1);
        __builtin_amdgcn_s_setprio(0);
    }
    bf16x8 vfa[NCC], vfb[NCC];
#pragma unroll
    for (int cc = 0; cc < NCC; ++cc) {
        vfa[cc] = *(const bf16x8*)(VL + l31 * 64 + ((((cc << 1) | hi) ^ swz) << 3));
        vfb[cc] = *(const bf16x8*)(VL + (32 + l31) * 64 + ((((cc << 1) | hi) ^ swz) << 3));
    }
    if constexpr (DMODE == 2) {
#pragma unroll
        for (int r = 0; r < 16; ++r) {
            int key = (r & 3) + 8 * (r >> 2) + 4 * hi;
            if (key > l31) s0[r] = -1e30f;
        }
    }
    if constexpr (DMODE == 1) {
#pragma unroll
        for (int r = 0; r < 16; ++r) {
            int key = (r & 3) + 8 * (r >> 2) + 4 * hi;
            if (key > l31) s1[r] = -1e30f;
        }
    }
    float t8[8];
    if constexpr (DMODE == 2) {
#pragma unroll
        for (int r = 0; r < 8; ++r) t8[r] = fmaxf(s0[r], s0[r + 8]);
    } else {
#pragma unroll
        for (int r = 0; r < 8; ++r)
            t8[r] = fmaxf(fmaxf(s0[r], s0[r + 8]), fmaxf(s1[r], s1[r + 8]));
    }
#pragma unroll
    for (int r = 0; r < 4; ++r) t8[r] = fmaxf(t8[r], t8[r + 4]);
    float pm = fmaxf(fmaxf(t8[0], t8[1]), fmaxf(t8[2], t8[3]));
    pm = fmaxf(pm, __shfl_xor(pm, 32, 64));

    if (!__all(pm - m <= 11.5f)) {  // deferred rescale (T13), 8*log2e
        float mn = fmaxf(m, pm);
        float al = exp2fast(m - mn);
        m = mn;
        l *= al;
#pragma unroll
        for (int r = 0; r < 16; ++r) {
            int qr = (r & 3) + 8 * (r >> 2) + 4 * hi;
            float aq = __shfl(al, qr, 64);
            o0[r] *= aq;
            o1[r] *= aq;
        }
    }
#pragma unroll
    for (int r = 0; r < 16; ++r) s0[r] = exp2fast(s0[r] - m);
    if constexpr (DMODE != 2) {
#pragma unroll
        for (int r = 0; r < 16; ++r) s1[r] = exp2fast(s1[r] - m);
    }
    float u8[8];
    if constexpr (DMODE == 2) {
#pragma unroll
        for (int r = 0; r < 8; ++r) u8[r] = s0[r] + s0[r + 8];
    } else {
#pragma unroll
        for (int r = 0; r < 8; ++r) u8[r] = (s0[r] + s0[r + 8]) + (s1[r] + s1[r + 8]);
    }
#pragma unroll
    for (int r = 0; r < 4; ++r) u8[r] = u8[r] + u8[r + 4];
    float ps = (u8[0] + u8[1]) + (u8[2] + u8[3]);
    l += ps + __shfl_xor(ps, 32, 64);

    __builtin_amdgcn_s_setprio(1);
#pragma unroll
    for (int cc = 0; cc < NCC; ++cc) {
        const f32x16& ph = (cc < 2) ? s0 : s1;
        const int bse = (cc & 1) * 8;
        uint x0 = pkbf(ph[bse + 0], ph[bse + 1]);
        uint x1 = pkbf(ph[bse + 2], ph[bse + 3]);
        uint y0 = pkbf(ph[bse + 4], ph[bse + 5]);
        uint y1 = pkbf(ph[bse + 6], ph[bse + 7]);
        uint sx0 = __shfl_xor(x0, 32, 64), sx1 = __shfl_xor(x1, 32, 64);
        uint sy0 = __shfl_xor(y0, 32, 64), sy1 = __shfl_xor(y1, 32, 64);
        u32x4 wv;
        wv.x = hi ? sy0 : x0;
        wv.y = hi ? sy1 : x1;
        wv.z = hi ? y0 : sx0;
        wv.w = hi ? y1 : sx1;
        bf16x8 pa = __builtin_bit_cast(bf16x8, wv);
        o0 = MFMA32(pa, vfa[cc], o0);
        o1 = MFMA32(pa, vfb[cc], o1);
    }
    __builtin_amdgcn_s_setprio(0);
}

__global__ __launch_bounds__(256) void attn_fwd(const bf16* __restrict__ Q,
                                                const bf16* __restrict__ K,
                                                const bf16* __restrict__ Vt,
                                                bf16* __restrict__ O) {
    __shared__ __align__(16) bf16 Kl[2][64 * 64];
    __shared__ __align__(16) bf16 Vl[2][64 * 64];

    const int g = blockIdx.x;
    const int lo = g & 255;
    const int xcd = lo & 7, jj = lo >> 3;
    const int hb = xcd * 4 + (jj & 3);
    const int qhi = 15 - (jj >> 2);
    const int qb = (g < 256) ? qhi : 15 - qhi;
    const int h = hb & 15, b = hb >> 4;

    const int tid = threadIdx.x, lane = tid & 63, w = tid >> 6;
    const int l31 = lane & 31, hi = lane >> 5;
    const int q0 = qb * 128 + w * 32;

    const bf16* Qp = Q + (size_t)b * T * E + h * Dh;
    const bf16* Kp = K + (size_t)b * T * E + h * Dh;
    const bf16* Vp = Vt + ((size_t)b * E + h * Dh) * T;

    const int rsub = lane >> 3;
    const int csw = (lane & 7) ^ rsub;
    const int swz = (l31 & 7);

    bf16x8 qf[4];
#pragma unroll
    for (int t = 0; t < 4; ++t)
        qf[t] = *(const bf16x8*)(Qp + (size_t)(q0 + l31) * E + t * 16 + hi * 8);

    f32x16 o0 = {}, o1 = {};
    float m = -1e30f, l = 0.f;
    const int ktD = 2 * qb + (w >> 1);
    const int nK2 = 2 * qb + 2;

#pragma unroll
    for (int ii = 0; ii < 2; ++ii)
        gll16(Kp + (size_t)(16 * w + 8 * ii + rsub) * E + csw * 8, &Kl[0][(2 * w + ii) * 512]);
#pragma unroll
    for (int ii = 0; ii < 2; ++ii)
        gll16(Vp + (size_t)(16 * w + 8 * ii + rsub) * T + csw * 8, &Vl[0][(2 * w + ii) * 512]);

    int cur = 0;
#pragma unroll 1
    for (int K2 = 0; K2 < nK2; ++K2) {
        if (K2 + 1 < nK2) {
            const int kb = (K2 + 1) * 64;
            const bf16* Kg = Kp + (size_t)kb * E;
            const bf16* Vg = Vp + kb;
            bf16* dK = &Kl[cur ^ 1][0];
            bf16* dV = &Vl[cur ^ 1][0];
#pragma unroll
            for (int ii = 0; ii < 2; ++ii)
                gll16(Kg + (size_t)(16 * w + 8 * ii + rsub) * E + csw * 8, dK + (2 * w + ii) * 512);
#pragma unroll
            for (int ii = 0; ii < 2; ++ii)
                gll16(Vg + (size_t)(16 * w + 8 * ii + rsub) * T + csw * 8, dV + (2 * w + ii) * 512);
            asm volatile("s_waitcnt vmcnt(4)" ::: "memory");
        } else {
            asm volatile("s_waitcnt vmcnt(0)" ::: "memory");
        }
        __builtin_amdgcn_s_barrier();
        asm volatile("" ::: "memory");

        const bf16* KL = &Kl[cur][0];
        const bf16* VL = &Vl[cur][0];
        if (K2 < ktD) {
            attn_tile64<0>(KL, VL, l31, hi, swz, qf, o0, o1, m, l);
        } else if (K2 == ktD) {
            if (w & 1)
                attn_tile64<1>(KL, VL, l31, hi, swz, qf, o0, o1, m, l);
            else
                attn_tile64<2>(KL, VL, l31, hi, swz, qf, o0, o1, m, l);
        }
        asm volatile("" ::: "memory");
        __builtin_amdgcn_s_barrier();
        cur ^= 1;
    }

    bf16* Op = O + (size_t)b * T * E + h * Dh;
#pragma unroll
    for (int r = 0; r < 16; ++r) {
        int qr = (r & 3) + 8 * (r >> 2) + 4 * hi;
        float lq = __shfl(l, qr, 64);
        float inv = 1.0f / lq;
        Op[(size_t)(q0 + qr) * E + l31] = (bf16)(o0[r] * inv);
        Op[(size_t)(q0 + qr) * E + 32 + l31] = (bf16)(o1[r] * inv);
    }
}

extern "C" void kernel_launch(void* const* d_in, const int* in_sizes, int n_in,
                              void* d_out, int out_size, void* d_ws, size_t ws_size,
                              hipStream_t stream) {
    const float* k_in = (const float*)d_in[0];
    const float* q_in = (const float*)d_in[1];
    const float* v_in = (const float*)d_in[2];
    const float* Wk = (const float*)d_in[3];
    const float* Wq = (const float*)d_in[4];
    const float* Wv = (const float*)d_in[5];
    const float* Wo = (const float*)d_in[6];
    const float* bo = (const float*)d_in[7];
    float* out = (float*)d_out;

    const size_t NE = (size_t)Bsz * T * E;  // 4M
    const size_t NW = (size_t)E * E;        // 1M
    bf16* ws = (bf16*)d_ws;
    bf16* Qb = ws;           // [B*T][E]  (pre-scaled by QSCALE)
    bf16* Kb = ws + NE;      // [B*T][E]
    bf16* Vt = ws + 2 * NE;  // [B][E][T]  (pre-transposed V)
    bf16* Ab = ws + 3 * NE;  // attn out
    bf16* Wqc = ws + 4 * NE;
    bf16* Wkc = Wqc + NW;
    bf16* Wvc = Wkc + NW;
    bf16* Woc = Wvc + NW;

    const bool planB = ws_size >= (4 * NE + 4 * NW) * sizeof(bf16);  // 40 MB

    if (planB) {
        cvt_w<<<512, 256, 0, stream>>>(Wq, Wk, Wv, Wo, Wqc, Wkc, Wvc, Woc);
        proj_qkv<<<1536, 256, 0, stream>>>(q_in, k_in, v_in, Wqc, Wkc, Wvc, Qb, Kb, Vt);
        attn_fwd<<<dim3(512), 256, 0, stream>>>(Qb, Kb, Vt, Ab);
        out_proj_db<<<512, 256, 0, stream>>>(Ab, Woc, out, bo);
    } else {
        qkv_proj_fb<<<768, 256, 0, stream>>>(q_in, k_in, v_in, Wq, Wk, Wv, Qb, Kb, Vt);
        attn_fwd<<<dim3(512), 256, 0, stream>>>(Qb, Kb, Vt, Ab);
        out_proj_fb<<<512, 256, 0, stream>>>(Ab, Wo, out, bo);
    }
}

// Round 19
// 120.151 us; speedup vs baseline: 1.0228x; 1.0228x over previous
//
#include <hip/hip_runtime.h>
#include <stdint.h>

typedef __bf16 bf16;
typedef bf16 bf16x8 __attribute__((ext_vector_type(8)));
typedef bf16 bf16x4 __attribute__((ext_vector_type(4)));
typedef float f32x4 __attribute__((ext_vector_type(4)));
typedef float f32x16 __attribute__((ext_vector_type(16)));
typedef unsigned int uint;
typedef uint u32x4 __attribute__((ext_vector_type(4)));

#define MFMA16(a, b, c) __builtin_amdgcn_mfma_f32_16x16x32_bf16(a, b, c, 0, 0, 0)
#define MFMA32(a, b, c) __builtin_amdgcn_mfma_f32_32x32x16_bf16(a, b, c, 0, 0, 0)

static constexpr int Bsz = 2, T = 2048, E = 1024, H = 16, Dh = 64;
// softmax scale folded into Q at projection; exp2-domain: 1/sqrt(64) * log2(e)
static constexpr float QSCALE = 0.125f * 1.44269504088896f;

__device__ __forceinline__ float exp2fast(float x) {
#if __has_builtin(__builtin_amdgcn_exp2f)
    return __builtin_amdgcn_exp2f(x);
#else
    return exp2f(x);
#endif
}

// async global->LDS, 16B per lane. LDS dest must be wave-uniform base (HW adds lane*16).
__device__ __forceinline__ void gll16(const bf16* g, bf16* l) {
    __builtin_amdgcn_global_load_lds((const __attribute__((address_space(1))) uint*)g,
                                     (__attribute__((address_space(3))) uint*)l, 16, 0, 0);
}

// ---- bf16 tile: ROWS x 64, swizzled LDS[r][c8] = G[r][c8^(r&7)] (attn-verified) ----
template <int ROWS>
__device__ __forceinline__ void stage_b16(bf16* lds, const bf16* g, int ldg, int wave, int lane) {
    const int rsub = lane >> 3;         // row within 8-row slab
    const int csw = (lane & 7) ^ rsub;  // pre-swizzled source chunk
#pragma unroll
    for (int i = 0; i < ROWS / 32; ++i) {
        const int row = wave * (ROWS / 4) + i * 8;  // wave-uniform slab base
        gll16(g + (size_t)(row + rsub) * ldg + csw * 8, lds + row * 64);
    }
}
__device__ __forceinline__ bf16x8 frag_b16(const bf16* lds, int r, int cc) {
    return *(const bf16x8*)(lds + r * 64 + ((cc ^ (r & 7)) << 3));
}

// ---- fp32 tile (fallback path only) ----
template <int ROWS>
__device__ __forceinline__ void stage_f32lds(float* lds, const float* g, int ldg,
                                             int wave, int lane) {
    const int rsub = lane >> 4;
#pragma unroll
    for (int i = 0; i < ROWS / 16; ++i) {
        const int slab = wave * (ROWS / 16) + i;
        const int row0 = slab * 4;
        const int src = (lane & 15) ^ ((((slab & 3)) << 2) | rsub);
        gll16((const bf16*)(g + (size_t)(row0 + rsub) * ldg + src * 4),
              (bf16*)(lds + row0 * 64));
    }
}
__device__ __forceinline__ bf16x8 frag_f32(const float* lds, int r, int lc0) {
    const f32x4 u0 = *(const f32x4*)(lds + r * 64 + ((lc0 ^ (r & 15)) << 2));
    const f32x4 u1 = *(const f32x4*)(lds + r * 64 + (((lc0 + 1) ^ (r & 15)) << 2));
    bf16x8 a = {(bf16)u0.x, (bf16)u0.y, (bf16)u0.z, (bf16)u0.w,
                (bf16)u1.x, (bf16)u1.y, (bf16)u1.z, (bf16)u1.w};
    return a;
}

// ---- Double-buffered all-bf16 GEMM body: Y[M,N] = A[M,K] @ B[N,K]^T (+bias).
// Counted-vmcnt pipeline (attn-proven): next tile's global_load_lds stay in
// flight across the barrier; only the current tile's loads are waited on.
template <int MF, int NF, bool OUTF32>
__device__ __forceinline__ void gemm_dbuf(bf16* smem, const bf16* A, const bf16* B,
                                          bf16* Yb, float* Yf, const float* bias,
                                          int m0, int n0, int K, int ldy, float oscale) {
    constexpr int BM = MF * 32, BN = NF * 32;
    constexpr int ABUF = BM * 64, SET = ABUF + BN * 64;
    const int tid = threadIdx.x, lane = tid & 63, wave = tid >> 6;
    const int wm = wave >> 1, wn = wave & 1;
    const int fr = lane & 15, kg16 = lane >> 4;

    f32x4 acc[MF][NF] = {};

    // prologue: stage tile 0 into set 0
    stage_b16<BM>(smem, A + (size_t)m0 * K, K, wave, lane);
    stage_b16<BN>(smem + ABUF, B + (size_t)n0 * K, K, wave, lane);

    const int NS = K / 64;
    int cur = 0;
#pragma unroll 1
    for (int s = 0; s < NS; ++s) {
        if (s + 1 < NS) {
            bf16* dst = smem + (cur ^ 1) * SET;
            stage_b16<BM>(dst, A + (size_t)m0 * K + (s + 1) * 64, K, wave, lane);
            stage_b16<BN>(dst + ABUF, B + (size_t)n0 * K + (s + 1) * 64, K, wave, lane);
            if constexpr (MF + NF == 8)
                asm volatile("s_waitcnt vmcnt(8)" ::: "memory");  // cur landed; next in flight
            else
                asm volatile("s_waitcnt vmcnt(6)" ::: "memory");
        } else {
            asm volatile("s_waitcnt vmcnt(0)" ::: "memory");
        }
        __builtin_amdgcn_s_barrier();
        asm volatile("" ::: "memory");

        const bf16* At = smem + cur * SET;
        const bf16* Bt = At + ABUF;
#pragma unroll
        for (int kk = 0; kk < 64; kk += 32) {
            bf16x8 af[MF], bfr[NF];
#pragma unroll
            for (int f = 0; f < MF; ++f)
                af[f] = frag_b16(At, wm * (BM / 2) + f * 16 + fr, (kk >> 3) + kg16);
#pragma unroll
            for (int f = 0; f < NF; ++f)
                bfr[f] = frag_b16(Bt, wn * (BN / 2) + f * 16 + fr, (kk >> 3) + kg16);
            __builtin_amdgcn_s_setprio(1);
#pragma unroll
            for (int mf = 0; mf < MF; ++mf)
#pragma unroll
                for (int nf = 0; nf < NF; ++nf)
                    acc[mf][nf] = MFMA16(af[mf], bfr[nf], acc[mf][nf]);
            __builtin_amdgcn_s_setprio(0);
        }
        asm volatile("" ::: "memory");
        __builtin_amdgcn_s_barrier();
        cur ^= 1;
    }
    const int rb = (lane >> 4) << 2;
#pragma unroll
    for (int mf = 0; mf < MF; ++mf)
#pragma unroll
        for (int nf = 0; nf < NF; ++nf) {
            int n = n0 + wn * (BN / 2) + nf * 16 + fr;
            float bn = 0.f;
            if constexpr (OUTF32) bn = bias[n];
#pragma unroll
            for (int r = 0; r < 4; ++r) {
                int mm = m0 + wm * (BM / 2) + mf * 16 + rb + r;
                float v = acc[mf][nf][r];
                if constexpr (OUTF32)
                    Yf[(size_t)mm * ldy + n] = v + bn;
                else
                    Yb[(size_t)mm * ldy + n] = (bf16)(v * oscale);
            }
        }
}

// ---- Single-buffer fallback body (only used when ws < 40 MB) ----
template <bool AF32, bool BF32, int MF, int NF, bool OUTF32>
__device__ __forceinline__ void gemm_body(char* smem, const void* Ap, const void* Bp,
                                          bf16* Yb, float* Yf, const float* bias,
                                          int m0, int n0, int K, int ldy, float oscale) {
    constexpr int BM = MF * 32, BN = NF * 32;
    constexpr int ASZ = BM * 64 * (AF32 ? 4 : 2);
    const int tid = threadIdx.x, lane = tid & 63, wave = tid >> 6;
    const int wm = wave >> 1, wn = wave & 1;
    const int fr = lane & 15, kg16 = lane >> 4;
    f32x4 acc[MF][NF] = {};
    for (int k0 = 0; k0 < K; k0 += 64) {
        if constexpr (AF32)
            stage_f32lds<BM>((float*)smem, (const float*)Ap + (size_t)m0 * K + k0, K, wave, lane);
        else
            stage_b16<BM>((bf16*)smem, (const bf16*)Ap + (size_t)m0 * K + k0, K, wave, lane);
        if constexpr (BF32)
            stage_f32lds<BN>((float*)(smem + ASZ), (const float*)Bp + (size_t)n0 * K + k0,
                             K, wave, lane);
        else
            stage_b16<BN>((bf16*)(smem + ASZ), (const bf16*)Bp + (size_t)n0 * K + k0,
                          K, wave, lane);
        __syncthreads();
#pragma unroll
        for (int kk = 0; kk < 64; kk += 32) {
            bf16x8 af[MF], bfr[NF];
#pragma unroll
            for (int f = 0; f < MF; ++f) {
                const int r = wm * (BM / 2) + f * 16 + fr;
                if constexpr (AF32)
                    af[f] = frag_f32((const float*)smem, r, (kk >> 2) + (kg16 << 1));
                else
                    af[f] = frag_b16((const bf16*)smem, r, (kk >> 3) + kg16);
            }
#pragma unroll
            for (int f = 0; f < NF; ++f) {
                const int r = wn * (BN / 2) + f * 16 + fr;
                if constexpr (BF32)
                    bfr[f] = frag_f32((const float*)(smem + ASZ), r, (kk >> 2) + (kg16 << 1));
                else
                    bfr[f] = frag_b16((const bf16*)(smem + ASZ), r, (kk >> 3) + kg16);
            }
#pragma unroll
            for (int mf = 0; mf < MF; ++mf)
#pragma unroll
                for (int nf = 0; nf < NF; ++nf)
                    acc[mf][nf] = MFMA16(af[mf], bfr[nf], acc[mf][nf]);
        }
        __syncthreads();
    }
    const int rb = (lane >> 4) << 2;
#pragma unroll
    for (int mf = 0; mf < MF; ++mf)
#pragma unroll
        for (int nf = 0; nf < NF; ++nf) {
            int n = n0 + wn * (BN / 2) + nf * 16 + fr;
            float bn = 0.f;
            if constexpr (OUTF32) bn = bias[n];
#pragma unroll
            for (int r = 0; r < 4; ++r) {
                int mm = m0 + wm * (BM / 2) + mf * 16 + rb + r;
                float v = acc[mf][nf][r];
                if constexpr (OUTF32)
                    Yf[(size_t)mm * ldy + n] = v + bn;
                else
                    Yb[(size_t)mm * ldy + n] = (bf16)(v * oscale);
            }
        }
}

// ---- conversion passes (fp32 -> bf16), grid-stride float4 ----
// planC: single pass for q,k,v + 4 weights.
__global__ __launch_bounds__(256) void cvt_all7(const float* q, const float* k, const float* v,
                                                const float* Wq, const float* Wk,
                                                const float* Wv, const float* Wo,
                                                bf16* qc, bf16* kc, bf16* vc,
                                                bf16* Wqc, bf16* Wkc, bf16* Wvc, bf16* Woc) {
    const size_t NX = (size_t)Bsz * T * E, NW = (size_t)E * E;
    const size_t tot = (3 * NX + 4 * NW) >> 2;
    for (size_t t = (size_t)blockIdx.x * 256 + threadIdx.x; t < tot;
         t += (size_t)gridDim.x * 256) {
        size_t i = t << 2;
        const float* s;
        bf16* d;
        size_t off;
        if (i < 3 * NX) {
            size_t w = i / NX;
            off = i - w * NX;
            s = w == 0 ? q : (w == 1 ? k : v);
            d = w == 0 ? qc : (w == 1 ? kc : vc);
        } else {
            size_t j = i - 3 * NX;
            size_t w = j / NW;
            off = j - w * NW;
            s = w == 0 ? Wq : (w == 1 ? Wk : (w == 2 ? Wv : Wo));
            d = w == 0 ? Wqc : (w == 1 ? Wkc : (w == 2 ? Wvc : Woc));
        }
        const float4 x = *(const float4*)(s + off);
        bf16x4 y = {(bf16)x.x, (bf16)x.y, (bf16)x.z, (bf16)x.w};
        *(bf16x4*)(d + off) = y;
    }
}
// planB split passes (aliased buffers force the two-phase order)
__global__ __launch_bounds__(256) void cvt_qk(const float* q, const float* k,
                                              const float* Wq, const float* Wk,
                                              bf16* qc, bf16* kc, bf16* Wqc, bf16* Wkc) {
    const size_t NX = (size_t)Bsz * T * E, NW = (size_t)E * E;
    const size_t n1 = NX, n2 = 2 * NX, n3 = 2 * NX + NW, tot = (2 * NX + 2 * NW) >> 2;
    for (size_t t = (size_t)blockIdx.x * 256 + threadIdx.x; t < tot;
         t += (size_t)gridDim.x * 256) {
        size_t i = t << 2;
        const float* s;
        bf16* d;
        size_t off;
        if (i < n1) { s = q; d = qc; off = i; }
        else if (i < n2) { s = k; d = kc; off = i - n1; }
        else if (i < n3) { s = Wq; d = Wqc; off = i - n2; }
        else { s = Wk; d = Wkc; off = i - n3; }
        const float4 x = *(const float4*)(s + off);
        bf16x4 y = {(bf16)x.x, (bf16)x.y, (bf16)x.z, (bf16)x.w};
        *(bf16x4*)(d + off) = y;
    }
}
__global__ __launch_bounds__(256) void cvt_vw(const float* v, const float* Wv, const float* Wo,
                                              bf16* vc, bf16* Wvc, bf16* Woc) {
    const size_t NX = (size_t)Bsz * T * E, NW = (size_t)E * E;
    const size_t n1 = NX, n2 = NX + NW, tot = (NX + 2 * NW) >> 2;
    for (size_t t = (size_t)blockIdx.x * 256 + threadIdx.x; t < tot;
         t += (size_t)gridDim.x * 256) {
        size_t i = t << 2;
        const float* s;
        bf16* d;
        size_t off;
        if (i < n1) { s = v; d = vc; off = i; }
        else if (i < n2) { s = Wv; d = Wvc; off = i - n1; }
        else { s = Wo; d = Woc; off = i - n2; }
        const float4 x = *(const float4*)(s + off);
        bf16x4 y = {(bf16)x.x, (bf16)x.y, (bf16)x.z, (bf16)x.w};
        *(bf16x4*)(d + off) = y;
    }
}

// ---- dbuf projection kernels ----
// Q/K: 512 blocks, XCD-swizzled, 64 KB LDS dbuf -> 2 blocks/CU.
__global__ __launch_bounds__(256) void proj_qk(const bf16* qc, const bf16* kc,
                                               const bf16* Wqc, const bf16* Wkc,
                                               bf16* Qb, bf16* Kb) {
    __shared__ __align__(16) bf16 smem[2 * (128 * 64 + 128 * 64)];  // 64 KB
    const int bid = blockIdx.x;
    const int wid = (bid & 7) * 64 + (bid >> 3);  // 512 % 8 == 0: bijective
    const int s = wid >> 8;                       // 0=Q (QSCALE), 1=K
    const int t = wid & 255;
    const int m0 = (t >> 3) * 128, n0 = (t & 7) * 128;
    gemm_dbuf<4, 4, false>(smem, s ? kc : qc, s ? Wkc : Wqc, s ? Kb : Qb,
                           nullptr, nullptr, m0, n0, E, E, s ? 1.0f : QSCALE);
}
// V^T: Vt_b[E][T] = Wv @ v_b^T. 128x64 tiles -> 512 blocks (2/CU), 48 KB dbuf.
__global__ __launch_bounds__(256) void proj_v(const bf16* Wvc, const bf16* vc, bf16* Vt) {
    __shared__ __align__(16) bf16 smem[2 * (128 * 64 + 64 * 64)];  // 48 KB
    const int bid = blockIdx.x;
    const int wid = (bid & 7) * 64 + (bid >> 3);  // 512 % 8 == 0: bijective
    const int b = wid >> 8, rr = wid & 255;
    const int m0 = (rr >> 5) * 128, n0 = (rr & 31) * 64;
    gemm_dbuf<4, 2, false>(smem, Wvc, vc + (size_t)b * T * E, Vt + (size_t)b * E * T,
                           nullptr, nullptr, m0, n0, E, T, 1.0f);
}
// Output projection dbuf: 48 KB.
__global__ __launch_bounds__(256) void out_proj_db(const bf16* Xb, const bf16* W16,
                                                   float* Y, const float* bias) {
    __shared__ __align__(16) bf16 smem[2 * (64 * 64 + 128 * 64)];  // 48 KB
    const int bid = blockIdx.x;
    const int wid = (bid & 7) * 64 + (bid >> 3);  // 512 % 8 == 0: bijective
    const int m0 = (wid >> 3) * 64, n0 = (wid & 7) * 128;
    gemm_dbuf<2, 4, true>(smem, Xb, W16, nullptr, Y, bias, m0, n0, E, E, 1.0f);
}

// ---- fallback (ws < 40 MB): single-buffer fused path ----
__global__ __launch_bounds__(256) void qkv_proj_fb(
    const float* q32, const float* k32, const float* v32,
    const float* Wq32, const float* Wk32, const float* Wv32,
    bf16* Qb, bf16* Kb, bf16* Vt) {
    __shared__ __align__(16) char smem[64 * 1024];
    const int bid = blockIdx.x;
    const int wid = (bid & 7) * 96 + (bid >> 3);
    if (wid < 512) {
        int s = wid >> 8;
        int t = wid & 255;
        int m0 = (t >> 3) * 128, n0 = (t & 7) * 128;
        gemm_body<true, true, 4, 4, false>(smem, s ? k32 : q32, s ? Wk32 : Wq32,
                                           s ? Kb : Qb, nullptr, nullptr, m0, n0, E, E,
                                           s ? 1.0f : QSCALE);
    } else {
        int r = wid - 512;
        int b = r >> 7, rr = r & 127;
        int m0 = (rr >> 4) * 128, n0 = (rr & 15) * 128;
        gemm_body<true, true, 4, 4, false>(smem, Wv32, v32 + (size_t)b * T * E,
                                           Vt + (size_t)b * E * T, nullptr, nullptr,
                                           m0, n0, E, T, 1.0f);
    }
}
__global__ __launch_bounds__(256) void out_proj_fb(const bf16* Xb, const float* W32,
                                                   float* Y, const float* bias) {
    __shared__ __align__(16) char smem[40 * 1024];
    const int bid = blockIdx.x;
    const int wid = (bid & 7) * 64 + (bid >> 3);
    const int m0 = (wid >> 3) * 64, n0 = (wid & 7) * 128;
    gemm_body<false, true, 2, 4, true>(smem, Xb, W32, nullptr, Y, bias, m0, n0, E, E, 1.0f);
}

// ---------------- Attention: flash, shared LDS-staged K/V tiles ------------
__device__ __forceinline__ uint pkbf(float a, float b) {
    uint16_t x = __builtin_bit_cast(uint16_t, (bf16)a);
    uint16_t y = __builtin_bit_cast(uint16_t, (bf16)b);
    return (uint)x | ((uint)y << 16);
}

template <int DMODE>
__device__ __forceinline__ void attn_tile64(const bf16* KL, const bf16* VL,
                                            int l31, int hi, int swz,
                                            const bf16x8 (&qf)[4],
                                            f32x16& o0, f32x16& o1, float& m, float& l) {
    constexpr int NCC = (DMODE == 2) ? 2 : 4;
    f32x16 s0 = {}, s1 = {};
    {
        bf16x8 kf[4];
#pragma unroll
        for (int t = 0; t < 4; ++t)
            kf[t] = *(const bf16x8*)(KL + l31 * 64 + ((((t << 1) | hi) ^ swz) << 3));
        __builtin_amdgcn_s_setprio(1);
#pragma unroll
        for (int t = 0; t < 4; ++t) s0 = MFMA32(kf[t], qf[t], s0);
        __builtin_amdgcn_s_setprio(0);
    }
    if constexpr (DMODE != 2) {
        bf16x8 kf[4];
#pragma unroll
        for (int t = 0; t < 4; ++t)
            kf[t] = *(const bf16x8*)(KL + (32 + l31) * 64 + ((((t << 1) | hi) ^ swz) << 3));
        __builtin_amdgcn_s_setprio(1);
#pragma unroll
        for (int t = 0; t < 4; ++t) s1 = MFMA32(kf[t], qf[t], s1);
        __builtin_amdgcn_s_setprio(0);
    }
    bf16x8 vfa[NCC], vfb[NCC];
#pragma unroll
    for (int cc = 0; cc < NCC; ++cc) {
        vfa[cc] = *(const bf16x8*)(VL + l31 * 64 + ((((cc << 1) | hi) ^ swz) << 3));
        vfb[cc] = *(const bf16x8*)(VL + (32 + l31) * 64 + ((((cc << 1) | hi) ^ swz) << 3));
    }
    if constexpr (DMODE == 2) {
#pragma unroll
        for (int r = 0; r < 16; ++r) {
            int key = (r & 3) + 8 * (r >> 2) + 4 * hi;
            if (key > l31) s0[r] = -1e30f;
        }
    }
    if constexpr (DMODE == 1) {
#pragma unroll
        for (int r = 0; r < 16; ++r) {
            int key = (r & 3) + 8 * (r >> 2) + 4 * hi;
            if (key > l31) s1[r] = -1e30f;
        }
    }
    float t8[8];
    if constexpr (DMODE == 2) {
#pragma unroll
        for (int r = 0; r < 8; ++r) t8[r] = fmaxf(s0[r], s0[r + 8]);
    } else {
#pragma unroll
        for (int r = 0; r < 8; ++r)
            t8[r] = fmaxf(fmaxf(s0[r], s0[r + 8]), fmaxf(s1[r], s1[r + 8]));
    }
#pragma unroll
    for (int r = 0; r < 4; ++r) t8[r] = fmaxf(t8[r], t8[r + 4]);
    float pm = fmaxf(fmaxf(t8[0], t8[1]), fmaxf(t8[2], t8[3]));
    pm = fmaxf(pm, __shfl_xor(pm, 32, 64));

    if (!__all(pm - m <= 11.5f)) {  // deferred rescale (T13), 8*log2e
        float mn = fmaxf(m, pm);
        float al = exp2fast(m - mn);
        m = mn;
        l *= al;
#pragma unroll
        for (int r = 0; r < 16; ++r) {
            int qr = (r & 3) + 8 * (r >> 2) + 4 * hi;
            float aq = __shfl(al, qr, 64);
            o0[r] *= aq;
            o1[r] *= aq;
        }
    }
#pragma unroll
    for (int r = 0; r < 16; ++r) s0[r] = exp2fast(s0[r] - m);
    if constexpr (DMODE != 2) {
#pragma unroll
        for (int r = 0; r < 16; ++r) s1[r] = exp2fast(s1[r] - m);
    }
    float u8[8];
    if constexpr (DMODE == 2) {
#pragma unroll
        for (int r = 0; r < 8; ++r) u8[r] = s0[r] + s0[r + 8];
    } else {
#pragma unroll
        for (int r = 0; r < 8; ++r) u8[r] = (s0[r] + s0[r + 8]) + (s1[r] + s1[r + 8]);
    }
#pragma unroll
    for (int r = 0; r < 4; ++r) u8[r] = u8[r] + u8[r + 4];
    float ps = (u8[0] + u8[1]) + (u8[2] + u8[3]);
    l += ps + __shfl_xor(ps, 32, 64);

    __builtin_amdgcn_s_setprio(1);
#pragma unroll
    for (int cc = 0; cc < NCC; ++cc) {
        const f32x16& ph = (cc < 2) ? s0 : s1;
        const int bse = (cc & 1) * 8;
        uint x0 = pkbf(ph[bse + 0], ph[bse + 1]);
        uint x1 = pkbf(ph[bse + 2], ph[bse + 3]);
        uint y0 = pkbf(ph[bse + 4], ph[bse + 5]);
        uint y1 = pkbf(ph[bse + 6], ph[bse + 7]);
        uint sx0 = __shfl_xor(x0, 32, 64), sx1 = __shfl_xor(x1, 32, 64);
        uint sy0 = __shfl_xor(y0, 32, 64), sy1 = __shfl_xor(y1, 32, 64);
        u32x4 wv;
        wv.x = hi ? sy0 : x0;
        wv.y = hi ? sy1 : x1;
        wv.z = hi ? y0 : sx0;
        wv.w = hi ? y1 : sx1;
        bf16x8 pa = __builtin_bit_cast(bf16x8, wv);
        o0 = MFMA32(pa, vfa[cc], o0);
        o1 = MFMA32(pa, vfb[cc], o1);
    }
    __builtin_amdgcn_s_setprio(0);
}

__global__ __launch_bounds__(256) void attn_fwd(const bf16* __restrict__ Q,
                                                const bf16* __restrict__ K,
                                                const bf16* __restrict__ Vt,
                                                bf16* __restrict__ O) {
    __shared__ __align__(16) bf16 Kl[2][64 * 64];
    __shared__ __align__(16) bf16 Vl[2][64 * 64];

    const int g = blockIdx.x;
    const int lo = g & 255;
    const int xcd = lo & 7, jj = lo >> 3;
    const int hb = xcd * 4 + (jj & 3);
    const int qhi = 15 - (jj >> 2);
    const int qb = (g < 256) ? qhi : 15 - qhi;
    const int h = hb & 15, b = hb >> 4;

    const int tid = threadIdx.x, lane = tid & 63, w = tid >> 6;
    const int l31 = lane & 31, hi = lane >> 5;
    const int q0 = qb * 128 + w * 32;

    const bf16* Qp = Q + (size_t)b * T * E + h * Dh;
    const bf16* Kp = K + (size_t)b * T * E + h * Dh;
    const bf16* Vp = Vt + ((size_t)b * E + h * Dh) * T;

    const int rsub = lane >> 3;
    const int csw = (lane & 7) ^ rsub;
    const int swz = (l31 & 7);

    bf16x8 qf[4];
#pragma unroll
    for (int t = 0; t < 4; ++t)
        qf[t] = *(const bf16x8*)(Qp + (size_t)(q0 + l31) * E + t * 16 + hi * 8);

    f32x16 o0 = {}, o1 = {};
    float m = -1e30f, l = 0.f;
    const int ktD = 2 * qb + (w >> 1);
    const int nK2 = 2 * qb + 2;

#pragma unroll
    for (int ii = 0; ii < 2; ++ii)
        gll16(Kp + (size_t)(16 * w + 8 * ii + rsub) * E + csw * 8, &Kl[0][(2 * w + ii) * 512]);
#pragma unroll
    for (int ii = 0; ii < 2; ++ii)
        gll16(Vp + (size_t)(16 * w + 8 * ii + rsub) * T + csw * 8, &Vl[0][(2 * w + ii) * 512]);

    int cur = 0;
#pragma unroll 1
    for (int K2 = 0; K2 < nK2; ++K2) {
        if (K2 + 1 < nK2) {
            const int kb = (K2 + 1) * 64;
            const bf16* Kg = Kp + (size_t)kb * E;
            const bf16* Vg = Vp + kb;
            bf16* dK = &Kl[cur ^ 1][0];
            bf16* dV = &Vl[cur ^ 1][0];
#pragma unroll
            for (int ii = 0; ii < 2; ++ii)
                gll16(Kg + (size_t)(16 * w + 8 * ii + rsub) * E + csw * 8, dK + (2 * w + ii) * 512);
#pragma unroll
            for (int ii = 0; ii < 2; ++ii)
                gll16(Vg + (size_t)(16 * w + 8 * ii + rsub) * T + csw * 8, dV + (2 * w + ii) * 512);
            asm volatile("s_waitcnt vmcnt(4)" ::: "memory");
        } else {
            asm volatile("s_waitcnt vmcnt(0)" ::: "memory");
        }
        __builtin_amdgcn_s_barrier();
        asm volatile("" ::: "memory");

        const bf16* KL = &Kl[cur][0];
        const bf16* VL = &Vl[cur][0];
        if (K2 < ktD) {
            attn_tile64<0>(KL, VL, l31, hi, swz, qf, o0, o1, m, l);
        } else if (K2 == ktD) {
            if (w & 1)
                attn_tile64<1>(KL, VL, l31, hi, swz, qf, o0, o1, m, l);
            else
                attn_tile64<2>(KL, VL, l31, hi, swz, qf, o0, o1, m, l);
        }
        asm volatile("" ::: "memory");
        __builtin_amdgcn_s_barrier();
        cur ^= 1;
    }

    bf16* Op = O + (size_t)b * T * E + h * Dh;
#pragma unroll
    for (int r = 0; r < 16; ++r) {
        int qr = (r & 3) + 8 * (r >> 2) + 4 * hi;
        float lq = __shfl(l, qr, 64);
        float inv = 1.0f / lq;
        Op[(size_t)(q0 + qr) * E + l31] = (bf16)(o0[r] * inv);
        Op[(size_t)(q0 + qr) * E + 32 + l31] = (bf16)(o1[r] * inv);
    }
}

extern "C" void kernel_launch(void* const* d_in, const int* in_sizes, int n_in,
                              void* d_out, int out_size, void* d_ws, size_t ws_size,
                              hipStream_t stream) {
    const float* k_in = (const float*)d_in[0];
    const float* q_in = (const float*)d_in[1];
    const float* v_in = (const float*)d_in[2];
    const float* Wk = (const float*)d_in[3];
    const float* Wq = (const float*)d_in[4];
    const float* Wv = (const float*)d_in[5];
    const float* Wo = (const float*)d_in[6];
    const float* bo = (const float*)d_in[7];
    float* out = (float*)d_out;

    const size_t NE = (size_t)Bsz * T * E;  // 4M
    const size_t NW = (size_t)E * E;        // 1M
    bf16* ws = (bf16*)d_ws;
    bf16* Qb = ws;           // [B*T][E]  (pre-scaled by QSCALE)
    bf16* Kb = ws + NE;      // [B*T][E]
    bf16* Vt = ws + 2 * NE;  // [B][E][T] (planB: also kc scratch before proj_v)
    bf16* Ab = ws + 3 * NE;  // attn out (planB: also qc, then vc scratch)
    bf16* Wqc = ws + 4 * NE;
    bf16* Wkc = Wqc + NW;
    bf16* Wvc = Wkc + NW;
    bf16* Woc = Wvc + NW;

    const bool planC = ws_size >= (5 * NE + 4 * NW) * sizeof(bf16);  // 48 MB
    const bool planB = ws_size >= (4 * NE + 4 * NW) * sizeof(bf16);  // 40 MB

    if (planC) {
        bf16* vc = ws + 4 * NE + 4 * NW;  // own 8 MB slot
        bf16* qc = Ab;                    // dead until attn writes Ab
        bf16* kc = Vt;                    // dead until proj_v writes Vt
        cvt_all7<<<2048, 256, 0, stream>>>(q_in, k_in, v_in, Wq, Wk, Wv, Wo,
                                           qc, kc, vc, Wqc, Wkc, Wvc, Woc);
        proj_qk<<<512, 256, 0, stream>>>(qc, kc, Wqc, Wkc, Qb, Kb);
        proj_v<<<512, 256, 0, stream>>>(Wvc, vc, Vt);  // overwrites dead kc
        attn_fwd<<<dim3(512), 256, 0, stream>>>(Qb, Kb, Vt, Ab);
        out_proj_db<<<512, 256, 0, stream>>>(Ab, Woc, out, bo);
    } else if (planB) {
        bf16* qc = Ab;  // dead until attn writes Ab
        bf16* kc = Vt;  // dead until proj_v writes Vt
        bf16* vc = Ab;  // qc dead after proj_qk
        cvt_qk<<<1024, 256, 0, stream>>>(q_in, k_in, Wq, Wk, qc, kc, Wqc, Wkc);
        proj_qk<<<512, 256, 0, stream>>>(qc, kc, Wqc, Wkc, Qb, Kb);
        cvt_vw<<<1024, 256, 0, stream>>>(v_in, Wv, Wo, vc, Wvc, Woc);
        proj_v<<<512, 256, 0, stream>>>(Wvc, vc, Vt);
        attn_fwd<<<dim3(512), 256, 0, stream>>>(Qb, Kb, Vt, Ab);
        out_proj_db<<<512, 256, 0, stream>>>(Ab, Woc, out, bo);
    } else {
        qkv_proj_fb<<<768, 256, 0, stream>>>(q_in, k_in, v_in, Wq, Wk, Wv, Qb, Kb, Vt);
        attn_fwd<<<dim3(512), 256, 0, stream>>>(Qb, Kb, Vt, Ab);
        out_proj_fb<<<512, 256, 0, stream>>>(Ab, Wo, out, bo);
    }
}